// Round 11
// baseline (1100.296 us; speedup 1.0000x reference)
//
#include <hip/hip_runtime.h>
#include <hip/hip_bf16.h>

// Problem constants
#define NSEQ 2048
#define NB   4
#define DIM  2048
#define HN   1024          // heads = DIM/2
#define FC   6144          // 3*DIM feat cols
#define MROWS 8192         // NSEQ*NB
#define CHUNKS 64
#define CLEN 32            // NSEQ/CHUNKS
#define NCH  4096          // NB*HN channels

typedef __bf16 bf16x8_t __attribute__((ext_vector_type(8)));
typedef float  f32x4_t  __attribute__((ext_vector_type(4)));

__device__ __forceinline__ float sigm(float x){ return 1.f/(1.f + __expf(-x)); }
__device__ __forceinline__ float bflo(unsigned p){ return __uint_as_float(p << 16); }
__device__ __forceinline__ float bfhi(unsigned p){ return __uint_as_float(p & 0xffff0000u); }
__device__ __forceinline__ float ubf(unsigned short u){ return __uint_as_float(((unsigned)u) << 16); }
__device__ __forceinline__ unsigned short f2bf(float f){
  union { __hip_bfloat16 h; unsigned short u; } cv;
  cv.h = __float2bfloat16(f);
  return cv.u;
}

// ---------------------------------------------------------------- convert f32 -> bf16
__global__ __launch_bounds__(256) void cvt_bf16_4(const float4* __restrict__ in,
                                                  ushort4* __restrict__ out, int n4){
  int i = blockIdx.x * blockDim.x + threadIdx.x;
  int st = gridDim.x * blockDim.x;
  for (; i < n4; i += st){
    float4 v = in[i];
    ushort4 r;
    r.x = f2bf(v.x); r.y = f2bf(v.y); r.z = f2bf(v.z); r.w = f2bf(v.w);
    out[i] = r;
  }
}

// ---------------------------------------------------------------- bf16 NT GEMM + bias / LN-epilogue
// OCCUPANCY round: r3/r7/r9 all measured 43% MfmaUtil at 2 waves/SIMD across three
// different schedules -> per-wave MFMA issue cadence (~10cy/instr/wave) is the cap,
// not scheduling. Fix: 2 LDS buffers (48KB) + __launch_bounds__(256,3) -> 3 blocks/CU
// = 3 waves/SIMD. r9's counted-vmcnt schedule kept at prefetch distance 1 (one iter
// ~1300cy > 900cy HBM): iter t = { barrier; stage(t+1)->buf[t^1]; vmcnt(6) [retires
// stage(t), keeps stage(t+1) in flight]; ds_read buf[t&1]; 32 MFMA }. Overwrite ledger:
// buf[t^1]'s readers (iter t-1) drained via their MFMA lgkm-waits before barrier(t);
// stage issued after barrier(t) -> cross-wave safe. asm "memory" orders reads below vmcnt.
// LDS layout r5/r9-verified conflict-free: 128B lines (2 rows x 32 el), granule
// glog=(row&1)*4+kg, phys=glog^(line&7); linear gl_lds dest + pre-swizzled source.
// LNE epilogue folds LayerNorm into GEMM2: out = rs_m*acc - rsmu_m*S1[n] + T[n].
__device__ __forceinline__ void gl_lds16(const void* g, void* l){
  __builtin_amdgcn_global_load_lds((const __attribute__((address_space(1))) void*)g,
                                   (__attribute__((address_space(3))) void*)l, 16, 0, 0);
}

template <typename OutT, bool LNE>
__global__ __launch_bounds__(256, 3) void gemm256x128(const __hip_bfloat16* __restrict__ A,
                                                      const __hip_bfloat16* __restrict__ B,
                                                      const float* __restrict__ bias,  // T[n] if LNE
                                                      const float* __restrict__ rs,
                                                      const float* __restrict__ rsmu,
                                                      const float* __restrict__ S1,
                                                      OutT* __restrict__ C,
                                                      int M, int N, int K, int nbx){
  // per buffer: A 256x32 (8192 el) + B 128x32 (4096 el) = 12288 el = 24KB; x2 = 48KB
  __shared__ __align__(16) __hip_bfloat16 smem[2*12288];
  const int tid  = threadIdx.x;
  const int wave = tid >> 6, lane = tid & 63;

  // T1: bijective XCD swizzle (gridDim.x % 8 == 0 by launch)
  const int cpx = gridDim.x >> 3;
  const int wg  = (blockIdx.x & 7) * cpx + (blockIdx.x >> 3);
  const int bx = wg % nbx, by = wg / nbx;
  const int m0 = by * 256, n0 = bx * 128;

  const int wr = wave >> 1, wc = wave & 1;   // 2M x 2N waves, wave-tile 128x64
  const int r  = lane & 15, q = lane >> 4;   // fragment row / k-granule
  const int NT = K >> 5;                     // BK=32

  // swizzled ds_read offsets (elems), r9-verified conflict-free
  int aoff[8], boff[4];
  #pragma unroll
  for (int f = 0; f < 8; ++f){
    int R = wr*128 + f*16 + r;
    aoff[f] = (R>>1)*64 + (((((R&1)<<2) | q) ^ ((R>>1)&7)) << 3);
  }
  #pragma unroll
  for (int n = 0; n < 4; ++n){
    int R = wc*64 + n*16 + r;
    boff[n] = (R>>1)*64 + (((((R&1)<<2) | q) ^ ((R>>1)&7)) << 3);
  }

  // stage one K-tile: A 1024 granules (4/thread) + B 512 (2/thread) = 6 gl_lds/thread;
  // linear LDS dest, pre-swizzled global source (same involution as the read offsets).
  auto stage = [&](int kt, int bo){
    #pragma unroll
    for (int i = 0; i < 4; ++i){
      int g = i*256 + tid;
      int line = g >> 3, glog = (g & 7) ^ (line & 7);
      int row = line*2 + (glog >> 2), kg = glog & 3;
      gl_lds16(A + (size_t)(m0 + row)*K + kt + kg*8, smem + bo + g*8);
    }
    #pragma unroll
    for (int i = 0; i < 2; ++i){
      int g = i*256 + tid;
      int line = g >> 3, glog = (g & 7) ^ (line & 7);
      int row = line*2 + (glog >> 2), kg = glog & 3;
      gl_lds16(B + (size_t)(n0 + row)*K + kt + kg*8, smem + bo + 8192 + g*8);
    }
  };

  f32x4_t acc[8][4] = {};

  stage(0, 0);
  for (int t = 0; t < NT; ++t){
    __builtin_amdgcn_s_barrier();
    if (t + 1 < NT){
      stage((t+1)*32, ((t+1)&1)*12288);
      asm volatile("s_waitcnt vmcnt(6)" ::: "memory");   // retire stage(t); keep stage(t+1)
    } else {
      asm volatile("s_waitcnt vmcnt(0)" ::: "memory");
    }
    const __hip_bfloat16* Ab = smem + (t&1)*12288;
    const __hip_bfloat16* Bb = Ab + 8192;
    bf16x8_t af[8], bfr[4];
    #pragma unroll
    for (int fn = 0; fn < 4; ++fn)
      bfr[fn] = *reinterpret_cast<const bf16x8_t*>(Bb + boff[fn]);
    #pragma unroll
    for (int fm = 0; fm < 8; ++fm)
      af[fm] = *reinterpret_cast<const bf16x8_t*>(Ab + aoff[fm]);
    __builtin_amdgcn_s_setprio(1);
    #pragma unroll
    for (int fm = 0; fm < 8; ++fm)
      #pragma unroll
      for (int fn = 0; fn < 4; ++fn)
        acc[fm][fn] = __builtin_amdgcn_mfma_f32_16x16x32_bf16(af[fm], bfr[fn], acc[fm][fn], 0, 0, 0);
    __builtin_amdgcn_s_setprio(0);
  }

  // epilogue: C/D layout col = lane&15, row = (lane>>4)*4 + j  (m89-verified)
  if constexpr (LNE){
    float S1c[4], Tc[4];
    #pragma unroll
    for (int fn = 0; fn < 4; ++fn){
      int col = n0 + wc*64 + fn*16 + r;
      S1c[fn] = S1[col];
      Tc[fn]  = bias[col];
    }
    #pragma unroll
    for (int fm = 0; fm < 8; ++fm){
      #pragma unroll
      for (int j = 0; j < 4; ++j){
        int row = m0 + wr*128 + fm*16 + q*4 + j;
        float rv = rs[row], rm = rsmu[row];
        #pragma unroll
        for (int fn = 0; fn < 4; ++fn){
          int col = n0 + wc*64 + fn*16 + r;
          C[(size_t)row*N + col] = (OutT)(rv*acc[fm][fn][j] - rm*S1c[fn] + Tc[fn]);
        }
      }
    }
  } else {
    #pragma unroll
    for (int fn = 0; fn < 4; ++fn){
      int col = n0 + wc*64 + fn*16 + r;
      float bv = bias[col];
      #pragma unroll
      for (int fm = 0; fm < 8; ++fm){
        int row0 = m0 + wr*128 + fm*16 + q*4;
        #pragma unroll
        for (int j = 0; j < 4; ++j){
          float v = acc[fm][fn][j] + bv;
          if constexpr (__is_same(OutT, float))
            C[(size_t)(row0 + j)*N + col] = v;
          else
            C[(size_t)(row0 + j)*N + col] = __float2bfloat16(v);
        }
      }
    }
  }
}

// ---------------------------------------------------------------- scan helpers
// feat viewed as uint pairs: row(n,b) = n*NB+b; uint offset = (n*NB+b)*3072 + h
//   + 0    -> inp pair (cols 2h, 2h+1)
//   + 1024 -> og  pair
//   + 2048 -> fg  pair
struct SV { float l0, l1, u00, u01, u10, u11; };
__device__ __forceinline__ SV stepp(unsigned pi, unsigned pf){
  SV s;
  s.l0 = sigm(bflo(pf)); s.l1 = sigm(bfhi(pf));
  float i0 = bflo(pi), i1 = bfhi(pi);
  i0 *= sigm(i0); i1 *= sigm(i1);            // silu
  float a0 = 1.f - s.l0, a1 = 1.f - s.l1;
  s.u00 = a0*i0; s.u01 = a0*i1; s.u10 = a1*i0; s.u11 = a1*i1;
  return s;
}

// S1: per-(channel, chunk) aggregates; one-pass feat read with register stash.
__global__ __launch_bounds__(256) void scan_agg(const unsigned* __restrict__ feat,
    float* __restrict__ aggP, float4* __restrict__ aggHF, float4* __restrict__ aggHR){
  int ch = blockIdx.x*256 + threadIdx.x;   // 0..4095  (b*HN + h)
  int c  = blockIdx.y;
  int b = ch >> 10, h = ch & 1023;
  int base = b*3072 + h;
  int n0 = c*CLEN;
  unsigned spi[CLEN], spf[CLEN];
  float P0 = 1.f, P1 = 1.f;
  float f00=0,f01=0,f10=0,f11=0;
  #pragma unroll
  for (int t = 0; t < CLEN; ++t){
    int rowu = (n0+t)*12288 + base;
    spi[t] = feat[rowu];
    spf[t] = feat[rowu + 2048];
    SV s = stepp(spi[t], spf[t]);
    f00 = s.l0*f00 + s.u00; f01 = s.l0*f01 + s.u01;
    f10 = s.l1*f10 + s.u10; f11 = s.l1*f11 + s.u11;
    P0 *= s.l0; P1 *= s.l1;
  }
  float r00=0,r01=0,r10=0,r11=0;
  #pragma unroll
  for (int t = CLEN-1; t >= 0; --t){
    SV s = stepp(spi[t], spf[t]);
    r00 = s.l0*r00 + s.u00; r01 = s.l0*r01 + s.u01;
    r10 = s.l1*r10 + s.u10; r11 = s.l1*r11 + s.u11;
  }
  aggP[c*8192 + ch*2]     = P0;
  aggP[c*8192 + ch*2 + 1] = P1;
  aggHF[c*4096 + ch] = make_float4(f00,f01,f10,f11);
  aggHR[c*4096 + ch] = make_float4(r00,r01,r10,r11);
}

// S2: serial scan over chunk aggregates -> per-chunk carry-in states.
__global__ __launch_bounds__(256) void scan_carry(const float* __restrict__ aggP,
    const float* __restrict__ aggHF, const float* __restrict__ aggHR,
    float* __restrict__ cF, float* __restrict__ cR){
  int t  = blockIdx.x*256 + threadIdx.x;   // 0..16383
  int pd = t >> 1;                         // ch*2 + d
  float s = 0.f;
  for (int c = 0; c < CHUNKS; ++c){
    cF[c*16384 + t] = s;
    s = aggP[c*8192 + pd]*s + aggHF[c*16384 + t];
  }
  s = 0.f;
  for (int c = CHUNKS-1; c >= 0; --c){
    cR[c*16384 + t] = s;
    s = aggP[c*8192 + pd]*s + aggHR[c*16384 + t];
  }
}

// S3 fused: fwd pass reads feat ONCE into a register stash (static-indexed) and
// accumulates gated outputs; rev pass reuses the stash; single packed bf16 write.
__global__ __launch_bounds__(256, 1) void scan_fr(const unsigned* __restrict__ feat,
    const float4* __restrict__ cF, const float4* __restrict__ cR,
    unsigned* __restrict__ obf){
  int ch = blockIdx.x*256 + threadIdx.x;
  int c  = blockIdx.y;
  int b = ch >> 10, h = ch & 1023;
  int base = b*3072 + h;
  unsigned spi[CLEN], spf[CLEN], spo[CLEN];
  float2 accv[CLEN];
  {
    float4 hv = cF[c*4096 + ch];
    float h00=hv.x, h01=hv.y, h10=hv.z, h11=hv.w;
    #pragma unroll
    for (int t = 0; t < CLEN; ++t){
      int rowu = (c*CLEN + t)*12288 + base;
      spi[t] = feat[rowu];
      spo[t] = feat[rowu + 1024];
      spf[t] = feat[rowu + 2048];
      SV s = stepp(spi[t], spf[t]);
      h00 = s.l0*h00 + s.u00; h01 = s.l0*h01 + s.u01;
      h10 = s.l1*h10 + s.u10; h11 = s.l1*h11 + s.u11;
      float g0 = sigm(bflo(spo[t])), g1 = sigm(bfhi(spo[t]));
      accv[t] = make_float2(g0*h00 + g1*h10, g0*h01 + g1*h11);
    }
  }
  {
    float4 hv = cR[c*4096 + ch];
    float h00=hv.x, h01=hv.y, h10=hv.z, h11=hv.w;
    #pragma unroll
    for (int t = CLEN-1; t >= 0; --t){
      SV s = stepp(spi[t], spf[t]);
      h00 = s.l0*h00 + s.u00; h01 = s.l0*h01 + s.u01;
      h10 = s.l1*h10 + s.u10; h11 = s.l1*h11 + s.u11;
      float g0 = sigm(bflo(spo[t])), g1 = sigm(bfhi(spo[t]));
      accv[t].x += g0*h00 + g1*h10;
      accv[t].y += g0*h01 + g1*h11;
    }
  }
  #pragma unroll
  for (int t = 0; t < CLEN; ++t){
    unsigned pk = (unsigned)f2bf(accv[t].x) | ((unsigned)f2bf(accv[t].y) << 16);
    obf[((c*CLEN + t)*NB + b)*1024 + h] = pk;
  }
}

// ---------------------------------------------------------------- per-row LN stats from bf16 o
__global__ __launch_bounds__(256) void rowstats(const unsigned* __restrict__ obf,
    float* __restrict__ rs, float* __restrict__ rsmu){
  int row = blockIdx.x, t = threadIdx.x;
  const uint4* p = (const uint4*)(obf + (size_t)row*1024);
  uint4 v = p[t];
  float s = 0.f, ss = 0.f;
  unsigned w[4] = {v.x, v.y, v.z, v.w};
  #pragma unroll
  for (int i = 0; i < 4; ++i){
    float a = bflo(w[i]), bb = bfhi(w[i]);
    s += a + bb; ss += a*a + bb*bb;
  }
  #pragma unroll
  for (int off = 32; off > 0; off >>= 1){
    s  += __shfl_down(s, off);
    ss += __shfl_down(ss, off);
  }
  __shared__ float red[8];
  int wv = t >> 6, ln = t & 63;
  if (ln == 0){ red[wv] = s; red[4 + wv] = ss; }
  __syncthreads();
  if (t == 0){
    float S  = (red[0] + red[1]) + (red[2] + red[3]);
    float SS = (red[4] + red[5]) + (red[6] + red[7]);
    float mu = S * (1.f/DIM);
    float rv = rsqrtf(SS * (1.f/DIM) - mu*mu + 1e-5f);
    rs[row] = rv;
    rsmu[row] = rv * mu;
  }
}

// ---------------------------------------------------------------- W_out prep: Wg = bf16(gamma*W),
// S1[n] = sum_k float(Wg[n,k]), T[n] = sum_k beta[k]*W[n,k] + b_out[n]
__global__ __launch_bounds__(256) void wprep(const float* __restrict__ W,
    const float* __restrict__ gamma, const float* __restrict__ beta,
    const float* __restrict__ bout, __hip_bfloat16* __restrict__ Wg,
    float* __restrict__ S1, float* __restrict__ T){
  int n = blockIdx.x, t = threadIdx.x;
  const float4* wr_ = (const float4*)(W + (size_t)n*DIM);
  const float4* gp  = (const float4*)gamma;
  const float4* bp  = (const float4*)beta;
  ushort4* og = (ushort4*)(Wg + (size_t)n*DIM);
  float s1 = 0.f, s2 = 0.f;
  #pragma unroll
  for (int i = 0; i < 2; ++i){
    int idx = t + i*256;
    float4 w = wr_[idx], g = gp[idx], b = bp[idx];
    ushort4 rr;
    rr.x = f2bf(w.x*g.x); rr.y = f2bf(w.y*g.y); rr.z = f2bf(w.z*g.z); rr.w = f2bf(w.w*g.w);
    og[idx] = rr;
    s1 += ubf(rr.x) + ubf(rr.y) + ubf(rr.z) + ubf(rr.w);
    s2 += b.x*w.x + b.y*w.y + b.z*w.z + b.w*w.w;
  }
  #pragma unroll
  for (int off = 32; off > 0; off >>= 1){
    s1 += __shfl_down(s1, off);
    s2 += __shfl_down(s2, off);
  }
  __shared__ float red[8];
  int wv = t >> 6, ln = t & 63;
  if (ln == 0){ red[wv] = s1; red[4 + wv] = s2; }
  __syncthreads();
  if (t == 0){
    S1[n] = (red[0] + red[1]) + (red[2] + red[3]);
    T[n]  = (red[4] + red[5]) + (red[6] + red[7]) + bout[n];
  }
}

// ---------------------------------------------------------------- launch
extern "C" void kernel_launch(void* const* d_in, const int* in_sizes, int n_in,
                              void* d_out, int out_size, void* d_ws, size_t ws_size,
                              hipStream_t stream){
  (void)in_sizes; (void)n_in; (void)out_size;
  const float* x     = (const float*)d_in[0];   // (N,B,D)
  const float* W_in  = (const float*)d_in[1];   // (3D,D)
  const float* b_in  = (const float*)d_in[2];   // (3D)
  const float* gamma = (const float*)d_in[3];   // (D)
  const float* beta  = (const float*)d_in[4];   // (D)
  const float* W_out = (const float*)d_in[5];   // (D,D)
  const float* b_out = (const float*)d_in[6];   // (D)
  float* out = (float*)d_out;                   // (N,B,D) fp32

  // ---- workspace layout with aliasing ----
  char* p = (char*)d_ws;
  auto carve = [&](size_t bytes) -> char* {
    char* r = p; p += (bytes + 255) & ~(size_t)255; return r;
  };
  __hip_bfloat16* feat = (__hip_bfloat16*)carve((size_t)MROWS*FC*2);      // 96 MiB
  char* U              = carve((size_t)MROWS*DIM*4);                      // 64 MiB
  __hip_bfloat16* Wg   = (__hip_bfloat16*)carve((size_t)DIM*DIM*2);       //  8 MiB
  float* aggP  = (float*)carve((size_t)CHUNKS*8192*4);                    //  2 MiB
  float* aggHF = (float*)carve((size_t)CHUNKS*16384*4);                   //  4 MiB
  float* aggHR = (float*)carve((size_t)CHUNKS*16384*4);                   //  4 MiB
  float* cF    = (float*)carve((size_t)CHUNKS*16384*4);                   //  4 MiB
  float* cR    = (float*)carve((size_t)CHUNKS*16384*4);                   //  4 MiB
  float* rs    = (float*)carve((size_t)MROWS*4);                          // 32 KiB
  float* rsmu  = (float*)carve((size_t)MROWS*4);                          // 32 KiB
  float* S1    = (float*)carve((size_t)DIM*4);                            //  8 KiB
  float* T     = (float*)carve((size_t)DIM*4);                            //  8 KiB
  if ((size_t)(p - (char*)d_ws) > ws_size) return;  // insufficient scratch

  __hip_bfloat16* xb  = (__hip_bfloat16*)U;                               // 32 MiB (phase 1)
  __hip_bfloat16* Wib = (__hip_bfloat16*)(U + (size_t)MROWS*DIM*2);       // 24 MiB (phase 1)
  unsigned* obf       = (unsigned*)U;                                     // 32 MiB (phase 2+)

  // 1) convert inputs to bf16 + W_out prep (gamma-folded, with S1/T reductions)
  cvt_bf16_4<<<2048, 256, 0, stream>>>((const float4*)x,    (ushort4*)xb,  MROWS*DIM/4);
  cvt_bf16_4<<<2048, 256, 0, stream>>>((const float4*)W_in, (ushort4*)Wib, FC*DIM/4);
  wprep<<<DIM, 256, 0, stream>>>(W_out, gamma, beta, b_out, Wg, S1, T);

  // 2) feat = x @ W_in^T + b_in   (8192 x 6144, K=2048), bf16 out; grid 1536 (%8==0)
  gemm256x128<__hip_bfloat16,false><<<1536, 256, 0, stream>>>(
      xb, Wib, b_in, nullptr, nullptr, nullptr, feat, MROWS, FC, 2048, FC/128);

  // 3) bidirectional chunked linear scan + gated output projection to obf (bf16)
  scan_agg  <<<dim3(NCH/256, CHUNKS), 256, 0, stream>>>((const unsigned*)feat, aggP, (float4*)aggHF, (float4*)aggHR);
  scan_carry<<<64, 256, 0, stream>>>(aggP, aggHF, aggHR, cF, cR);
  scan_fr   <<<dim3(NCH/256, CHUNKS), 256, 0, stream>>>((const unsigned*)feat, (const float4*)cF, (const float4*)cR, obf);

  // 4) per-row LN stats (LN itself folded into GEMM2's epilogue)
  rowstats<<<MROWS, 256, 0, stream>>>(obf, rs, rsmu);

  // 5) out = LN(o) @ (gamma*W_out)^T + ... via linearity; fp32 out; grid 512 (%8==0)
  gemm256x128<float,true><<<512, 256, 0, stream>>>(
      (const __hip_bfloat16*)obf, Wg, T, rs, rsmu, S1, out, MROWS, DIM, 2048, DIM/128);
}